// Round 1
// baseline (3254.938 us; speedup 1.0000x reference)
//
#include <hip/hip_runtime.h>

// GraphSAGE 3-layer forward, f32.
// Pipeline per layer: scatter-add h[src] -> msum[dst] (atomics), then
// fused (h @ Wself^T + (msum*recip_deg) @ Wneigh^T + b) [+ReLU] GEMM.
// deg/recip computed once (depends only on dst).

#define DIN 96

// ---- degree ----
__global__ void deg_kernel(const int* __restrict__ dst, float* __restrict__ deg, int nE) {
    int i = blockIdx.x * blockDim.x + threadIdx.x;
    if (i < nE) unsafeAtomicAdd(&deg[dst[i]], 1.0f);
}

__global__ void recip_kernel(float* __restrict__ deg, int nN) {
    int i = blockIdx.x * blockDim.x + threadIdx.x;
    if (i < nN) deg[i] = 1.0f / fmaxf(deg[i], 1.0f);
}

// ---- scatter: msum[dst[e], :] += h[src[e], :] ----
// thread = (edge, quad-of-4-floats); 24 quads per edge (96 dims).
__global__ void scatter_kernel(const float* __restrict__ h, const int* __restrict__ src,
                               const int* __restrict__ dst, float* __restrict__ msum, int nE) {
    int idx = blockIdx.x * blockDim.x + threadIdx.x;
    if (idx >= nE * 24) return;
    int e = idx / 24;
    int q = idx - e * 24;
    int s = src[e], d = dst[e];
    const float4 v = *reinterpret_cast<const float4*>(h + (size_t)s * DIN + q * 4);
    float* p = msum + (size_t)d * DIN + q * 4;
    unsafeAtomicAdd(p + 0, v.x);
    unsafeAtomicAdd(p + 1, v.y);
    unsafeAtomicAdd(p + 2, v.z);
    unsafeAtomicAdd(p + 3, v.w);
}

// ---- fused SAGE layer GEMM ----
// out[n, ob+o] = sum_k h[n,k]*Wself[ob+o,k] + hmean[n,k]*Wneigh[ob+o,k] + b[ob+o]
// Block: 256 threads, NB=32 nodes, OC outputs (grid.y = DOUT/OC).
// LDS: weights [OC][100] x2 + tiles [32][100] x2; pitch 100 -> stride mod 32 = 4,
// conflict-free float4 reads. Thread = (og in 0..15, pair pg in 0..15): 2 nodes,
// JS = OC/16 outputs each; weight LDS reads amortized over the node pair.
template<int DOUT, int OC, bool RELU>
__global__ __launch_bounds__(256)
void sage_gemm(const float* __restrict__ hin, const float* __restrict__ msum,
               const float* __restrict__ recip, const float* __restrict__ wself,
               const float* __restrict__ wneigh, const float* __restrict__ bias,
               float* __restrict__ hout, int nN) {
    constexpr int P = 100;   // LDS pitch in floats
    constexpr int NB = 32;   // nodes per block
    constexpr int JS = OC / 16;
    __shared__ float ws[OC][P];
    __shared__ float wn[OC][P];
    __shared__ float hs[NB][P];
    __shared__ float hm[NB][P];

    const int tid = threadIdx.x;
    const int n0 = blockIdx.x * NB;
    const int ob = blockIdx.y * OC;

    // stage weights (OC x 96, as 24 float4 per row)
    for (int t = tid; t < OC * 24; t += 256) {
        int o = t / 24, kq = t - o * 24;
        *reinterpret_cast<float4*>(&ws[o][kq * 4]) =
            *reinterpret_cast<const float4*>(wself + (size_t)(ob + o) * DIN + kq * 4);
        *reinterpret_cast<float4*>(&wn[o][kq * 4]) =
            *reinterpret_cast<const float4*>(wneigh + (size_t)(ob + o) * DIN + kq * 4);
    }
    // stage node tile: h and hmean = msum * recip
    for (int t = tid; t < NB * 24; t += 256) {
        int ni = t / 24, kq = t - ni * 24;
        int n = n0 + ni;
        float4 a = make_float4(0.f, 0.f, 0.f, 0.f);
        float4 m = make_float4(0.f, 0.f, 0.f, 0.f);
        if (n < nN) {
            a = *reinterpret_cast<const float4*>(hin + (size_t)n * DIN + kq * 4);
            float4 s = *reinterpret_cast<const float4*>(msum + (size_t)n * DIN + kq * 4);
            float r = recip[n];
            m = make_float4(s.x * r, s.y * r, s.z * r, s.w * r);
        }
        *reinterpret_cast<float4*>(&hs[ni][kq * 4]) = a;
        *reinterpret_cast<float4*>(&hm[ni][kq * 4]) = m;
    }
    __syncthreads();

    const int og = tid & 15;
    const int pg = tid >> 4;
    const int ni0 = pg * 2, ni1 = ni0 + 1;

    float acc0[JS], acc1[JS];
#pragma unroll
    for (int j = 0; j < JS; ++j) { acc0[j] = 0.f; acc1[j] = 0.f; }

#pragma unroll 4
    for (int kq = 0; kq < 24; ++kq) {
        float4 a0 = *reinterpret_cast<const float4*>(&hs[ni0][kq * 4]);
        float4 m0 = *reinterpret_cast<const float4*>(&hm[ni0][kq * 4]);
        float4 a1 = *reinterpret_cast<const float4*>(&hs[ni1][kq * 4]);
        float4 m1 = *reinterpret_cast<const float4*>(&hm[ni1][kq * 4]);
#pragma unroll
        for (int j = 0; j < JS; ++j) {
            int o = og + 16 * j;
            float4 w0 = *reinterpret_cast<const float4*>(&ws[o][kq * 4]);
            float4 w1 = *reinterpret_cast<const float4*>(&wn[o][kq * 4]);
            acc0[j] += a0.x * w0.x + a0.y * w0.y + a0.z * w0.z + a0.w * w0.w
                     + m0.x * w1.x + m0.y * w1.y + m0.z * w1.z + m0.w * w1.w;
            acc1[j] += a1.x * w0.x + a1.y * w0.y + a1.z * w0.z + a1.w * w0.w
                     + m1.x * w1.x + m1.y * w1.y + m1.z * w1.z + m1.w * w1.w;
        }
    }

    const int na = n0 + ni0, nb = n0 + ni1;
#pragma unroll
    for (int j = 0; j < JS; ++j) {
        int o = og + 16 * j;
        float bv = bias[ob + o];
        float v0 = acc0[j] + bv;
        float v1 = acc1[j] + bv;
        if (RELU) { v0 = fmaxf(v0, 0.f); v1 = fmaxf(v1, 0.f); }
        if (na < nN) hout[(size_t)na * DOUT + ob + o] = v0;
        if (nb < nN) hout[(size_t)nb * DOUT + ob + o] = v1;
    }
}

extern "C" void kernel_launch(void* const* d_in, const int* in_sizes, int n_in,
                              void* d_out, int out_size, void* d_ws, size_t ws_size,
                              hipStream_t stream) {
    const float* x   = (const float*)d_in[0];
    const int*   src = (const int*)d_in[1];
    const int*   dst = (const int*)d_in[2];
    const float* ws0 = (const float*)d_in[3];
    const float* wn0 = (const float*)d_in[4];
    const float* b0  = (const float*)d_in[5];
    const float* ws1 = (const float*)d_in[6];
    const float* wn1 = (const float*)d_in[7];
    const float* b1  = (const float*)d_in[8];
    const float* ws2 = (const float*)d_in[9];
    const float* wn2 = (const float*)d_in[10];
    const float* b2  = (const float*)d_in[11];
    float* out = (float*)d_out;

    const int nN = in_sizes[0] / DIN;   // 50000
    const int nE = in_sizes[1];         // 800000

    // workspace layout (f32): recip[50048] | msum[nN*96] | hA[nN*96] | hB[nN*96]
    float* recip = (float*)d_ws;
    float* msum  = recip + 50048;
    float* hA    = msum + (size_t)nN * DIN;
    float* hB    = hA + (size_t)nN * DIN;

    // degree -> reciprocal (depends only on dst; recomputed every call for determinism)
    hipMemsetAsync(recip, 0, (size_t)nN * sizeof(float), stream);
    deg_kernel<<<(nE + 255) / 256, 256, 0, stream>>>(dst, recip, nE);
    recip_kernel<<<(nN + 255) / 256, 256, 0, stream>>>(recip, nN);

    const int sgrid = (nE * 24 + 255) / 256;
    dim3 ggrid96((nN + 31) / 32, 2);   // DOUT=96, OC=48
    dim3 ggrid64((nN + 31) / 32, 2);   // DOUT=64, OC=32

    // ---- layer 0 ----
    hipMemsetAsync(msum, 0, (size_t)nN * DIN * sizeof(float), stream);
    scatter_kernel<<<sgrid, 256, 0, stream>>>(x, src, dst, msum, nE);
    sage_gemm<96, 48, true><<<ggrid96, 256, 0, stream>>>(x, msum, recip, ws0, wn0, b0, hA, nN);

    // ---- layer 1 ----
    hipMemsetAsync(msum, 0, (size_t)nN * DIN * sizeof(float), stream);
    scatter_kernel<<<sgrid, 256, 0, stream>>>(hA, src, dst, msum, nE);
    sage_gemm<96, 48, true><<<ggrid96, 256, 0, stream>>>(hA, msum, recip, ws1, wn1, b1, hB, nN);

    // ---- layer 2 ----
    hipMemsetAsync(msum, 0, (size_t)nN * DIN * sizeof(float), stream);
    scatter_kernel<<<sgrid, 256, 0, stream>>>(hB, src, dst, msum, nE);
    sage_gemm<64, 32, false><<<ggrid64, 256, 0, stream>>>(hB, msum, recip, ws2, wn2, b2, out, nN);
}

// Round 2
// 535.782 us; speedup vs baseline: 6.0751x; 6.0751x over previous
//
#include <hip/hip_runtime.h>

// GraphSAGE 3-layer forward, f32.
// Aggregation via CSR gather (built per call): deg histogram -> scan ->
// bucket fill (int atomics only), then per-layer gather (no atomics) +
// fused (h @ Wself^T + hmean @ Wneigh^T + b) [+ReLU] GEMM.

#define DIN 96

// ---- degree histogram (int) ----
__global__ void deg_kernel(const int* __restrict__ dst, int* __restrict__ deg, int nE) {
    int i = blockIdx.x * blockDim.x + threadIdx.x;
    if (i < nE) atomicAdd(&deg[dst[i]], 1);
}

// ---- single-block exclusive scan: offs[i] = sum deg[0..i-1]; cursor = copy ----
__global__ void scan_kernel(const int* __restrict__ deg, int* __restrict__ offs,
                            int* __restrict__ cursor, int nN) {
    __shared__ int part[256];
    const int tid = threadIdx.x;
    const int chunk = (nN + 255) / 256;
    const int lo = tid * chunk;
    const int hi = min(lo + chunk, nN);
    int s = 0;
    for (int i = lo; i < hi; ++i) s += deg[i];
    part[tid] = s;
    __syncthreads();
    for (int d = 1; d < 256; d <<= 1) {
        int v = 0;
        if (tid >= d) v = part[tid - d];
        __syncthreads();
        if (tid >= d) part[tid] += v;
        __syncthreads();
    }
    int base = (tid == 0) ? 0 : part[tid - 1];
    for (int i = lo; i < hi; ++i) {
        offs[i] = base;
        cursor[i] = base;
        base += deg[i];
    }
}

// ---- bucket fill: esrc[pos] = src[e], bucketed by dst[e] ----
__global__ void bucket_kernel(const int* __restrict__ src, const int* __restrict__ dst,
                              int* __restrict__ cursor, int* __restrict__ esrc, int nE) {
    int e = blockIdx.x * blockDim.x + threadIdx.x;
    if (e < nE) {
        int pos = atomicAdd(&cursor[dst[e]], 1);
        esrc[pos] = src[e];
    }
}

// ---- gather: hmean[n,:] = mean over in-edges of h[src,:] ----
// thread = (node, quad of 4 floats); 24 quads per node.
__global__ void gather_kernel(const float* __restrict__ h, const int* __restrict__ esrc,
                              const int* __restrict__ offs, const int* __restrict__ deg,
                              float* __restrict__ hmean, int nN) {
    int idx = blockIdx.x * blockDim.x + threadIdx.x;
    if (idx >= nN * 24) return;
    int n = idx / 24;
    int q = idx - n * 24;
    const int beg = offs[n];
    const int dg = deg[n];
    const float* hq = h + q * 4;
    float ax = 0.f, ay = 0.f, az = 0.f, aw = 0.f;
    for (int j = beg; j < beg + dg; ++j) {
        int s = esrc[j];
        const float4 v = *reinterpret_cast<const float4*>(hq + (size_t)s * DIN);
        ax += v.x; ay += v.y; az += v.z; aw += v.w;
    }
    const float r = 1.0f / (float)max(dg, 1);
    float4 o = make_float4(ax * r, ay * r, az * r, aw * r);
    *reinterpret_cast<float4*>(hmean + (size_t)n * DIN + q * 4) = o;
}

// ---- fused SAGE layer GEMM ----
// out[n, ob+o] = sum_k h[n,k]*Wself[ob+o,k] + hmean[n,k]*Wneigh[ob+o,k] + b[ob+o]
template<int DOUT, int OC, bool RELU>
__global__ __launch_bounds__(256)
void sage_gemm(const float* __restrict__ hin, const float* __restrict__ hmean,
               const float* __restrict__ wself, const float* __restrict__ wneigh,
               const float* __restrict__ bias, float* __restrict__ hout, int nN) {
    constexpr int P = 100;   // LDS pitch in floats
    constexpr int NB = 32;   // nodes per block
    constexpr int JS = OC / 16;
    __shared__ float ws[OC][P];
    __shared__ float wn[OC][P];
    __shared__ float hs[NB][P];
    __shared__ float hm[NB][P];

    const int tid = threadIdx.x;
    const int n0 = blockIdx.x * NB;
    const int ob = blockIdx.y * OC;

    for (int t = tid; t < OC * 24; t += 256) {
        int o = t / 24, kq = t - o * 24;
        *reinterpret_cast<float4*>(&ws[o][kq * 4]) =
            *reinterpret_cast<const float4*>(wself + (size_t)(ob + o) * DIN + kq * 4);
        *reinterpret_cast<float4*>(&wn[o][kq * 4]) =
            *reinterpret_cast<const float4*>(wneigh + (size_t)(ob + o) * DIN + kq * 4);
    }
    for (int t = tid; t < NB * 24; t += 256) {
        int ni = t / 24, kq = t - ni * 24;
        int n = n0 + ni;
        float4 a = make_float4(0.f, 0.f, 0.f, 0.f);
        float4 m = make_float4(0.f, 0.f, 0.f, 0.f);
        if (n < nN) {
            a = *reinterpret_cast<const float4*>(hin + (size_t)n * DIN + kq * 4);
            m = *reinterpret_cast<const float4*>(hmean + (size_t)n * DIN + kq * 4);
        }
        *reinterpret_cast<float4*>(&hs[ni][kq * 4]) = a;
        *reinterpret_cast<float4*>(&hm[ni][kq * 4]) = m;
    }
    __syncthreads();

    const int og = tid & 15;
    const int pg = tid >> 4;
    const int ni0 = pg * 2, ni1 = ni0 + 1;

    float acc0[JS], acc1[JS];
#pragma unroll
    for (int j = 0; j < JS; ++j) { acc0[j] = 0.f; acc1[j] = 0.f; }

#pragma unroll 4
    for (int kq = 0; kq < 24; ++kq) {
        float4 a0 = *reinterpret_cast<const float4*>(&hs[ni0][kq * 4]);
        float4 m0 = *reinterpret_cast<const float4*>(&hm[ni0][kq * 4]);
        float4 a1 = *reinterpret_cast<const float4*>(&hs[ni1][kq * 4]);
        float4 m1 = *reinterpret_cast<const float4*>(&hm[ni1][kq * 4]);
#pragma unroll
        for (int j = 0; j < JS; ++j) {
            int o = og + 16 * j;
            float4 w0 = *reinterpret_cast<const float4*>(&ws[o][kq * 4]);
            float4 w1 = *reinterpret_cast<const float4*>(&wn[o][kq * 4]);
            acc0[j] += a0.x * w0.x + a0.y * w0.y + a0.z * w0.z + a0.w * w0.w
                     + m0.x * w1.x + m0.y * w1.y + m0.z * w1.z + m0.w * w1.w;
            acc1[j] += a1.x * w0.x + a1.y * w0.y + a1.z * w0.z + a1.w * w0.w
                     + m1.x * w1.x + m1.y * w1.y + m1.z * w1.z + m1.w * w1.w;
        }
    }

    const int na = n0 + ni0, nb = n0 + ni1;
#pragma unroll
    for (int j = 0; j < JS; ++j) {
        int o = og + 16 * j;
        float bv = bias[ob + o];
        float v0 = acc0[j] + bv;
        float v1 = acc1[j] + bv;
        if (RELU) { v0 = fmaxf(v0, 0.f); v1 = fmaxf(v1, 0.f); }
        if (na < nN) hout[(size_t)na * DOUT + ob + o] = v0;
        if (nb < nN) hout[(size_t)nb * DOUT + ob + o] = v1;
    }
}

extern "C" void kernel_launch(void* const* d_in, const int* in_sizes, int n_in,
                              void* d_out, int out_size, void* d_ws, size_t ws_size,
                              hipStream_t stream) {
    const float* x   = (const float*)d_in[0];
    const int*   src = (const int*)d_in[1];
    const int*   dst = (const int*)d_in[2];
    const float* ws0 = (const float*)d_in[3];
    const float* wn0 = (const float*)d_in[4];
    const float* b0  = (const float*)d_in[5];
    const float* ws1 = (const float*)d_in[6];
    const float* wn1 = (const float*)d_in[7];
    const float* b1  = (const float*)d_in[8];
    const float* ws2 = (const float*)d_in[9];
    const float* wn2 = (const float*)d_in[10];
    const float* b2  = (const float*)d_in[11];
    float* out = (float*)d_out;

    const int nN = in_sizes[0] / DIN;   // 50000
    const int nE = in_sizes[1];         // 800000

    // workspace layout: deg[nN] offs[nN] cursor[nN] (int) | esrc[nE] (int)
    //                   | hmean[nN*96] | hA[nN*96] | hB[nN*96] (f32)
    int* deg    = (int*)d_ws;
    int* offs   = deg + 50048;
    int* cursor = offs + 50048;
    int* esrc   = cursor + 50048;
    float* hmean = (float*)(esrc + nE);
    float* hA    = hmean + (size_t)nN * DIN;
    float* hB    = hA + (size_t)nN * DIN;

    // ---- build CSR by dst (per call; int atomics only) ----
    hipMemsetAsync(deg, 0, (size_t)nN * sizeof(int), stream);
    deg_kernel<<<(nE + 255) / 256, 256, 0, stream>>>(dst, deg, nE);
    scan_kernel<<<1, 256, 0, stream>>>(deg, offs, cursor, nN);
    bucket_kernel<<<(nE + 255) / 256, 256, 0, stream>>>(src, dst, cursor, esrc, nE);

    const int ggrid = (nN * 24 + 255) / 256;
    dim3 ggrid96((nN + 31) / 32, 2);   // DOUT=96, OC=48
    dim3 ggrid64((nN + 31) / 32, 2);   // DOUT=64, OC=32

    // ---- layer 0 ----
    gather_kernel<<<ggrid, 256, 0, stream>>>(x, esrc, offs, deg, hmean, nN);
    sage_gemm<96, 48, true><<<ggrid96, 256, 0, stream>>>(x, hmean, ws0, wn0, b0, hA, nN);

    // ---- layer 1 ----
    gather_kernel<<<ggrid, 256, 0, stream>>>(hA, esrc, offs, deg, hmean, nN);
    sage_gemm<96, 48, true><<<ggrid96, 256, 0, stream>>>(hA, hmean, ws1, wn1, b1, hB, nN);

    // ---- layer 2 ----
    gather_kernel<<<ggrid, 256, 0, stream>>>(hB, esrc, offs, deg, hmean, nN);
    sage_gemm<64, 32, false><<<ggrid64, 256, 0, stream>>>(hB, hmean, ws2, wn2, b2, out, nN);
}

// Round 3
// 424.070 us; speedup vs baseline: 7.6755x; 1.2634x over previous
//
#include <hip/hip_runtime.h>

// GraphSAGE 3-layer forward, f32.
// Aggregation via CSR gather (built per call): deg histogram -> hierarchical
// scan (3 parallel kernels) -> bucket fill (int atomics only), then per-layer
// gather (no atomics) + fused (h @ Wself^T + hmean @ Wneigh^T + b) [+ReLU] GEMM.

#define DIN 96

// ---- degree histogram (int) ----
__global__ void deg_kernel(const int* __restrict__ dst, int* __restrict__ deg, int nE) {
    int i = blockIdx.x * blockDim.x + threadIdx.x;
    if (i < nE) atomicAdd(&deg[dst[i]], 1);
}

// ---- hierarchical exclusive scan, phase 1: per-block sums ----
__global__ void block_sum_kernel(const int* __restrict__ deg, int* __restrict__ bsum, int nN) {
    __shared__ int s[256];
    const int tid = threadIdx.x;
    int i = blockIdx.x * 256 + tid;
    s[tid] = (i < nN) ? deg[i] : 0;
    __syncthreads();
    for (int d = 128; d > 0; d >>= 1) {
        if (tid < d) s[tid] += s[tid + d];
        __syncthreads();
    }
    if (tid == 0) bsum[blockIdx.x] = s[0];
}

// ---- phase 2: exclusive scan of block sums (nB <= 256, single block) ----
__global__ void bsum_scan_kernel(int* __restrict__ bsum, int nB) {
    __shared__ int s[256];
    const int tid = threadIdx.x;
    int v = (tid < nB) ? bsum[tid] : 0;
    s[tid] = v;
    __syncthreads();
    for (int d = 1; d < 256; d <<= 1) {
        int t = (tid >= d) ? s[tid - d] : 0;
        __syncthreads();
        s[tid] += t;
        __syncthreads();
    }
    if (tid < nB) bsum[tid] = s[tid] - v;   // exclusive
}

// ---- phase 3: local exclusive scan + block base -> offs, cursor ----
__global__ void scan_apply_kernel(const int* __restrict__ deg, const int* __restrict__ bsum,
                                  int* __restrict__ offs, int* __restrict__ cursor, int nN) {
    __shared__ int s[256];
    const int tid = threadIdx.x;
    int i = blockIdx.x * 256 + tid;
    int v = (i < nN) ? deg[i] : 0;
    s[tid] = v;
    __syncthreads();
    for (int d = 1; d < 256; d <<= 1) {
        int t = (tid >= d) ? s[tid - d] : 0;
        __syncthreads();
        s[tid] += t;
        __syncthreads();
    }
    if (i < nN) {
        int o = bsum[blockIdx.x] + s[tid] - v;
        offs[i] = o;
        cursor[i] = o;
    }
}

// ---- bucket fill: esrc[pos] = src[e], bucketed by dst[e] ----
__global__ void bucket_kernel(const int* __restrict__ src, const int* __restrict__ dst,
                              int* __restrict__ cursor, int* __restrict__ esrc, int nE) {
    int e = blockIdx.x * blockDim.x + threadIdx.x;
    if (e < nE) {
        int pos = atomicAdd(&cursor[dst[e]], 1);
        esrc[pos] = src[e];
    }
}

// ---- gather: hmean[n,:] = mean over in-edges of h[src,:] ----
// thread = (node, quad of 4 floats); 24 quads per node.
__global__ void gather_kernel(const float* __restrict__ h, const int* __restrict__ esrc,
                              const int* __restrict__ offs, const int* __restrict__ deg,
                              float* __restrict__ hmean, int nN) {
    int idx = blockIdx.x * blockDim.x + threadIdx.x;
    if (idx >= nN * 24) return;
    int n = idx / 24;
    int q = idx - n * 24;
    const int beg = offs[n];
    const int dg = deg[n];
    const float* hq = h + q * 4;
    float ax = 0.f, ay = 0.f, az = 0.f, aw = 0.f;
    for (int j = beg; j < beg + dg; ++j) {
        int s = esrc[j];
        const float4 v = *reinterpret_cast<const float4*>(hq + (size_t)s * DIN);
        ax += v.x; ay += v.y; az += v.z; aw += v.w;
    }
    const float r = 1.0f / (float)max(dg, 1);
    float4 o = make_float4(ax * r, ay * r, az * r, aw * r);
    *reinterpret_cast<float4*>(hmean + (size_t)n * DIN + q * 4) = o;
}

// ---- fused SAGE layer GEMM ----
// out[n, ob+o] = sum_k h[n,k]*Wself[ob+o,k] + hmean[n,k]*Wneigh[ob+o,k] + b[ob+o]
template<int DOUT, int OC, bool RELU>
__global__ __launch_bounds__(256)
void sage_gemm(const float* __restrict__ hin, const float* __restrict__ hmean,
               const float* __restrict__ wself, const float* __restrict__ wneigh,
               const float* __restrict__ bias, float* __restrict__ hout, int nN) {
    constexpr int P = 100;   // LDS pitch in floats
    constexpr int NB = 32;   // nodes per block
    constexpr int JS = OC / 16;
    __shared__ float ws[OC][P];
    __shared__ float wn[OC][P];
    __shared__ float hs[NB][P];
    __shared__ float hm[NB][P];

    const int tid = threadIdx.x;
    const int n0 = blockIdx.x * NB;
    const int ob = blockIdx.y * OC;

    for (int t = tid; t < OC * 24; t += 256) {
        int o = t / 24, kq = t - o * 24;
        *reinterpret_cast<float4*>(&ws[o][kq * 4]) =
            *reinterpret_cast<const float4*>(wself + (size_t)(ob + o) * DIN + kq * 4);
        *reinterpret_cast<float4*>(&wn[o][kq * 4]) =
            *reinterpret_cast<const float4*>(wneigh + (size_t)(ob + o) * DIN + kq * 4);
    }
    for (int t = tid; t < NB * 24; t += 256) {
        int ni = t / 24, kq = t - ni * 24;
        int n = n0 + ni;
        float4 a = make_float4(0.f, 0.f, 0.f, 0.f);
        float4 m = make_float4(0.f, 0.f, 0.f, 0.f);
        if (n < nN) {
            a = *reinterpret_cast<const float4*>(hin + (size_t)n * DIN + kq * 4);
            m = *reinterpret_cast<const float4*>(hmean + (size_t)n * DIN + kq * 4);
        }
        *reinterpret_cast<float4*>(&hs[ni][kq * 4]) = a;
        *reinterpret_cast<float4*>(&hm[ni][kq * 4]) = m;
    }
    __syncthreads();

    const int og = tid & 15;
    const int pg = tid >> 4;
    const int ni0 = pg * 2, ni1 = ni0 + 1;

    float acc0[JS], acc1[JS];
#pragma unroll
    for (int j = 0; j < JS; ++j) { acc0[j] = 0.f; acc1[j] = 0.f; }

#pragma unroll 4
    for (int kq = 0; kq < 24; ++kq) {
        float4 a0 = *reinterpret_cast<const float4*>(&hs[ni0][kq * 4]);
        float4 m0 = *reinterpret_cast<const float4*>(&hm[ni0][kq * 4]);
        float4 a1 = *reinterpret_cast<const float4*>(&hs[ni1][kq * 4]);
        float4 m1 = *reinterpret_cast<const float4*>(&hm[ni1][kq * 4]);
#pragma unroll
        for (int j = 0; j < JS; ++j) {
            int o = og + 16 * j;
            float4 w0 = *reinterpret_cast<const float4*>(&ws[o][kq * 4]);
            float4 w1 = *reinterpret_cast<const float4*>(&wn[o][kq * 4]);
            acc0[j] += a0.x * w0.x + a0.y * w0.y + a0.z * w0.z + a0.w * w0.w
                     + m0.x * w1.x + m0.y * w1.y + m0.z * w1.z + m0.w * w1.w;
            acc1[j] += a1.x * w0.x + a1.y * w0.y + a1.z * w0.z + a1.w * w0.w
                     + m1.x * w1.x + m1.y * w1.y + m1.z * w1.z + m1.w * w1.w;
        }
    }

    const int na = n0 + ni0, nb = n0 + ni1;
#pragma unroll
    for (int j = 0; j < JS; ++j) {
        int o = og + 16 * j;
        float bv = bias[ob + o];
        float v0 = acc0[j] + bv;
        float v1 = acc1[j] + bv;
        if (RELU) { v0 = fmaxf(v0, 0.f); v1 = fmaxf(v1, 0.f); }
        if (na < nN) hout[(size_t)na * DOUT + ob + o] = v0;
        if (nb < nN) hout[(size_t)nb * DOUT + ob + o] = v1;
    }
}

extern "C" void kernel_launch(void* const* d_in, const int* in_sizes, int n_in,
                              void* d_out, int out_size, void* d_ws, size_t ws_size,
                              hipStream_t stream) {
    const float* x   = (const float*)d_in[0];
    const int*   src = (const int*)d_in[1];
    const int*   dst = (const int*)d_in[2];
    const float* ws0 = (const float*)d_in[3];
    const float* wn0 = (const float*)d_in[4];
    const float* b0  = (const float*)d_in[5];
    const float* ws1 = (const float*)d_in[6];
    const float* wn1 = (const float*)d_in[7];
    const float* b1  = (const float*)d_in[8];
    const float* ws2 = (const float*)d_in[9];
    const float* wn2 = (const float*)d_in[10];
    const float* b2  = (const float*)d_in[11];
    float* out = (float*)d_out;

    const int nN = in_sizes[0] / DIN;   // 50000
    const int nE = in_sizes[1];         // 800000
    const int nB = (nN + 255) / 256;    // 196 scan blocks (<= 256)

    // workspace: deg[nN] offs[nN] cursor[nN] bsum[256] (int) | esrc[nE] (int)
    //            | hmean[nN*96] | hA[nN*96] | hB[nN*96] (f32)
    int* deg    = (int*)d_ws;
    int* offs   = deg + 50048;
    int* cursor = offs + 50048;
    int* bsum   = cursor + 50048;
    int* esrc   = bsum + 256;
    float* hmean = (float*)(esrc + nE);
    float* hA    = hmean + (size_t)nN * DIN;
    float* hB    = hA + (size_t)nN * DIN;

    // ---- build CSR by dst (per call; int atomics only) ----
    hipMemsetAsync(deg, 0, (size_t)nN * sizeof(int), stream);
    deg_kernel<<<(nE + 255) / 256, 256, 0, stream>>>(dst, deg, nE);
    block_sum_kernel<<<nB, 256, 0, stream>>>(deg, bsum, nN);
    bsum_scan_kernel<<<1, 256, 0, stream>>>(bsum, nB);
    scan_apply_kernel<<<nB, 256, 0, stream>>>(deg, bsum, offs, cursor, nN);
    bucket_kernel<<<(nE + 255) / 256, 256, 0, stream>>>(src, dst, cursor, esrc, nE);

    const int ggrid = (nN * 24 + 255) / 256;
    dim3 ggrid96((nN + 31) / 32, 2);   // DOUT=96, OC=48
    dim3 ggrid64((nN + 31) / 32, 2);   // DOUT=64, OC=32

    // ---- layer 0 ----
    gather_kernel<<<ggrid, 256, 0, stream>>>(x, esrc, offs, deg, hmean, nN);
    sage_gemm<96, 48, true><<<ggrid96, 256, 0, stream>>>(x, hmean, ws0, wn0, b0, hA, nN);

    // ---- layer 1 ----
    gather_kernel<<<ggrid, 256, 0, stream>>>(hA, esrc, offs, deg, hmean, nN);
    sage_gemm<96, 48, true><<<ggrid96, 256, 0, stream>>>(hA, hmean, ws1, wn1, b1, hB, nN);

    // ---- layer 2 ----
    gather_kernel<<<ggrid, 256, 0, stream>>>(hB, esrc, offs, deg, hmean, nN);
    sage_gemm<64, 32, false><<<ggrid64, 256, 0, stream>>>(hB, hmean, ws2, wn2, b2, out, nN);
}